// Round 4
// baseline (253.732 us; speedup 1.0000x reference)
//
#include <hip/hip_runtime.h>

// Depthwise 3x3 conv (stride 1, pad 1), 2 filters per input channel,
// output channels interleaved [2c, 2c+1], + bias.
// x (32,192,56,56) f32; w1,w2 (C,9); bias (2C); out (32,384,56,56).
//
// R4: barrier-free register-rolling design. One thread = 4 cols x 14 rows
// of one plane (56 output px, both filters). 3-row rolling register buffer;
// 16 row loads (float4 + 2 L1-hit edge scalars), 28 nontemporal float4
// stores. Block = 448 threads (7 full waves, 8 planes), no LDS, no barrier.

#define CC 192
#define HH 56
#define WW 56
#define W4 14          // float4 segments per row
#define STRIPS 4       // vertical strips per plane
#define RPS 14         // rows per strip
#define PPB 8          // planes per block
#define TPB (PPB * 56) // 448 threads = 7 waves

typedef float f32x4 __attribute__((ext_vector_type(4)));

__global__ __launch_bounds__(TPB) void dwconv2_reg_kernel(
    const float* __restrict__ x,
    const float* __restrict__ w1,
    const float* __restrict__ w2,
    const float* __restrict__ bias,
    float* __restrict__ out)
{
    const int t     = threadIdx.x;
    const int w4    = t % W4;
    const int strip = (t / W4) % STRIPS;
    const int pl    = t / 56;
    const int bc    = blockIdx.x * PPB + pl;   // b*CC + c
    const int c     = bc % CC;

    // Per-channel weights (2 distinct addresses per wave -> L1 broadcast).
    float a1[9], a2[9];
#pragma unroll
    for (int i = 0; i < 9; ++i) { a1[i] = w1[c * 9 + i]; a2[i] = w2[c * 9 + i]; }
    const float b1 = bias[2 * c];
    const float b2 = bias[2 * c + 1];

    const int h0 = strip * RPS;
    const int w0 = w4 * 4;
    const float* xp = x + (size_t)bc * HH * WW + w0;          // col base of this segment
    float* op1 = out + (((size_t)bc * 2) * HH + h0) * WW + w0; // channel 2c
    float* op2 = op1 + (size_t)HH * WW;                        // channel 2c+1

    const bool has_left  = (w0 > 0);
    const bool has_right = (w0 + 4 < WW);

    // Rolling 3-row buffer, 6 cols each (image cols w0-1 .. w0+4).
    float r[3][6];

#define LOAD_ROW(hh, dst)                                                    \
    do {                                                                     \
        const int _hh = (hh);                                                \
        const bool _hv = (_hh >= 0) && (_hh < HH);                           \
        const float* _rp = xp + (size_t)_hh * WW;                            \
        f32x4 _v = {0.f, 0.f, 0.f, 0.f};                                     \
        if (_hv) _v = *(const f32x4*)_rp;                                    \
        (dst)[0] = (_hv && has_left)  ? _rp[-1] : 0.f;                       \
        (dst)[1] = _v.x; (dst)[2] = _v.y; (dst)[3] = _v.z; (dst)[4] = _v.w;  \
        (dst)[5] = (_hv && has_right) ? _rp[4]  : 0.f;                       \
    } while (0)

    LOAD_ROW(h0 - 1, r[0]);
    LOAD_ROW(h0,     r[1]);

#pragma unroll
    for (int j = 0; j < RPS; ++j) {
        LOAD_ROW(h0 + j + 1, r[(j + 2) % 3]);

        const float* top = r[(j + 0) % 3];
        const float* mid = r[(j + 1) % 3];
        const float* bot = r[(j + 2) % 3];

        float o1v[4], o2v[4];
#pragma unroll
        for (int p = 0; p < 4; ++p) { o1v[p] = b1; o2v[p] = b2; }

#pragma unroll
        for (int p = 0; p < 4; ++p) {
#pragma unroll
            for (int kc = 0; kc < 3; ++kc) {
                o1v[p] += top[p + kc] * a1[0 + kc];
                o1v[p] += mid[p + kc] * a1[3 + kc];
                o1v[p] += bot[p + kc] * a1[6 + kc];
                o2v[p] += top[p + kc] * a2[0 + kc];
                o2v[p] += mid[p + kc] * a2[3 + kc];
                o2v[p] += bot[p + kc] * a2[6 + kc];
            }
        }

        f32x4 s1; s1.x = o1v[0]; s1.y = o1v[1]; s1.z = o1v[2]; s1.w = o1v[3];
        f32x4 s2; s2.x = o2v[0]; s2.y = o2v[1]; s2.z = o2v[2]; s2.w = o2v[3];
        __builtin_nontemporal_store(s1, (f32x4*)(op1 + (size_t)j * WW));
        __builtin_nontemporal_store(s2, (f32x4*)(op2 + (size_t)j * WW));
    }
#undef LOAD_ROW
}

extern "C" void kernel_launch(void* const* d_in, const int* in_sizes, int n_in,
                              void* d_out, int out_size, void* d_ws, size_t ws_size,
                              hipStream_t stream) {
    const float* x  = (const float*)d_in[0];
    const float* w1 = (const float*)d_in[1];
    const float* w2 = (const float*)d_in[2];
    const float* bs = (const float*)d_in[3];
    float* out = (float*)d_out;

    const int planes = 32 * CC;          // 6144
    const int grid = planes / PPB;       // 768 blocks = 3 per CU
    dwconv2_reg_kernel<<<grid, TPB, 0, stream>>>(x, w1, w2, bs, out);
}